// Round 17
// baseline (298.939 us; speedup 1.0000x reference)
//
#include <hip/hip_runtime.h>
#include <hip/hip_bf16.h>
#include <math.h>

#define NTOK 16384
#define HDIM 1024
#define DSZ 32
#define DGZ 32
#define FMZ 64
#define NEXP 4
#define FFZ 2048

typedef __attribute__((ext_vector_type(4))) float f32x4;
typedef __attribute__((ext_vector_type(8))) short bf16x8;

__device__ __forceinline__ unsigned short f2bf(float f){
    union { float f; unsigned int u; } v; v.f = f;
    unsigned int r = (v.u + 0x7FFFu + ((v.u >> 16) & 1u)) >> 16;
    return (unsigned short)r;
}
__device__ __forceinline__ float gelu_f(float x){
    return 0.5f * x * (1.0f + erff(x * 0.70710678118654752440f));
}
__device__ __forceinline__ void gld_lds16(const void* g, void* s){
    __builtin_amdgcn_global_load_lds((const __attribute__((address_space(1))) unsigned int*)g,
                                     (__attribute__((address_space(3))) unsigned int*)s, 16, 0, 0);
}

// ---------------- kernel 1: both weight transposes in one launch (+ cnt zeroing) ----------------
__global__ __launch_bounds__(256) void k_transpose2(const float* __restrict__ W1,
        const float* __restrict__ W2, unsigned short* __restrict__ W1T,
        unsigned short* __restrict__ W2T, int* __restrict__ cnt){
    __shared__ float tile[32][33];
    if (blockIdx.x == 0 && blockIdx.y == 0 && blockIdx.z == 0 &&
        threadIdx.y == 0 && threadIdx.x < 4)
        cnt[threadIdx.x] = 0;
    int z = blockIdx.z;
    const float* in; unsigned short* out; int R, C, bx, by;
    if (z < 4){
        in = W1 + (size_t)z * HDIM * FFZ; out = W1T + (size_t)z * HDIM * FFZ;
        R = HDIM; C = FFZ; bx = blockIdx.x * 32; by = blockIdx.y * 32;
    } else {
        int e = z - 4;
        in = W2 + (size_t)e * FFZ * HDIM; out = W2T + (size_t)e * FFZ * HDIM;
        R = FFZ; C = HDIM; bx = blockIdx.y * 32; by = blockIdx.x * 32;
    }
    int x = threadIdx.x, y = threadIdx.y;
    #pragma unroll
    for (int i = 0; i < 32; i += 8)
        tile[y + i][x] = in[(size_t)(by + y + i) * C + (bx + x)];
    __syncthreads();
    #pragma unroll
    for (int i = 0; i < 32; i += 8)
        out[(size_t)(bx + y + i) * R + (by + x)] = f2bf(tile[x][y + i]);
}

// ---------------- kernel 2: fused routing (stats + route + h->bf16 conversion tail) ----------------
__global__ __launch_bounds__(256) void k_route(
    const float* __restrict__ h, const float* __restrict__ tok_emb,
    const float* __restrict__ ln_g, const float* __restrict__ ln_b,
    const float* __restrict__ Wg, const float* __restrict__ bg,
    const float* __restrict__ Wf, const float* __restrict__ bfv,
    const float* __restrict__ Wr, const float* __restrict__ br,
    float* __restrict__ tprob, int* __restrict__ list, int* __restrict__ cnt,
    float* __restrict__ imp_part, unsigned short* __restrict__ hbf)
{
    __shared__ __align__(16) char smem[62208];
    float* lgs  = (float*)(smem);
    float* lbs  = (float*)(smem + 4096);
    float (*hsT)[64]  = (float(*)[64])(smem + 8192);
    float (*wgs)[32]  = (float(*)[32])(smem + 24576);
    float (*gacc)[32] = (float(*)[32])(smem + 32768);
    float* mus = (float*)(smem + 40960);
    float* rss = (float*)(smem + 41216);
    float (*wrs)[4]     = (float(*)[4])(smem + 41472);
    float (*logit_s)[5] = (float(*)[5])(smem + 42496);
    float (*prob_s)[5]  = (float(*)[5])(smem + 43776);
    int* lcnt  = (int*)(smem + 45056);
    int* lbase = (int*)(smem + 45072);
    float (*agT)[64] = (float(*)[64])(smem);
    float (*wfs)[64] = (float(*)[64])(smem + 16384);
    float (*uT)[64]  = (float(*)[64])(smem + 45824);

    int tid = threadIdx.x;
    int t0 = blockIdx.x * 64;

    ((float4*)lgs)[tid] = ((const float4*)ln_g)[tid];
    ((float4*)lbs)[tid] = ((const float4*)ln_b)[tid];
    if (tid < 64) ((float4*)wrs)[tid] = ((const float4*)Wr)[tid];
    if (tid < 4) lcnt[tid] = 0;

    {
        int tokrow = tid >> 2, q4 = tid & 3;
        const float4* hp = (const float4*)(h + (size_t)(t0 + tokrow) * HDIM);
        float s = 0.f, s2 = 0.f;
        #pragma unroll 8
        for (int i = 0; i < 64; ++i){
            float4 v = hp[q4 + 4 * i];
            s  += v.x + v.y + v.z + v.w;
            s2 += v.x*v.x + v.y*v.y + v.z*v.z + v.w*v.w;
        }
        s  += __shfl_xor(s, 1, 64);  s2 += __shfl_xor(s2, 1, 64);
        s  += __shfl_xor(s, 2, 64);  s2 += __shfl_xor(s2, 2, 64);
        if (q4 == 0){
            float mu = s * (1.0f / HDIM);
            float var = fmaxf(s2 * (1.0f / HDIM) - mu * mu, 0.f);
            mus[tokrow] = mu;
            rss[tokrow] = 1.0f / sqrtf(var + 1e-5f);
        }
    }
    __syncthreads();

    int l = tid & 63, w = tid >> 6;
    int tg = l & 7, cg = l >> 3, q = w;
    float g_[8][4];
    #pragma unroll
    for (int i=0;i<8;++i){ g_[i][0]=0.f; g_[i][1]=0.f; g_[i][2]=0.f; g_[i][3]=0.f; }
    int tokrow = tid >> 2;
    float m_ = mus[tokrow], r_ = rss[tokrow];
    const float* hrow = h + (size_t)(t0 + tokrow) * HDIM;

    for (int k0 = 0; k0 < HDIM; k0 += 64){
        #pragma unroll
        for (int p = 0; p < 4; ++p){
            int f4 = (tid & 3) + 4 * p;
            float4 v = ((const float4*)(hrow + k0))[f4];
            int c = f4 * 4;
            hsT[c+0][tokrow] = (v.x - m_) * r_ * lgs[k0+c+0] + lbs[k0+c+0];
            hsT[c+1][tokrow] = (v.y - m_) * r_ * lgs[k0+c+1] + lbs[k0+c+1];
            hsT[c+2][tokrow] = (v.z - m_) * r_ * lgs[k0+c+2] + lbs[k0+c+2];
            hsT[c+3][tokrow] = (v.w - m_) * r_ * lgs[k0+c+3] + lbs[k0+c+3];
        }
        {
            int wgrow = tid >> 2;
            #pragma unroll
            for (int p = 0; p < 2; ++p){
                int f4 = (tid & 3) + 4 * p;
                ((float4*)wgs[wgrow])[f4] = ((const float4*)(Wg + (size_t)(k0 + wgrow) * DGZ))[f4];
            }
        }
        __syncthreads();
        #pragma unroll
        for (int kk16 = 0; kk16 < 16; ++kk16){
            int kk = q * 16 + kk16;
            float4 a0 = ((float4*)hsT[kk])[tg*2];
            float4 a1 = ((float4*)hsT[kk])[tg*2+1];
            float4 wv = ((float4*)wgs[kk])[cg];
            float av[8] = {a0.x,a0.y,a0.z,a0.w,a1.x,a1.y,a1.z,a1.w};
            float wj[4] = {wv.x,wv.y,wv.z,wv.w};
            #pragma unroll
            for (int i=0;i<8;++i){
                g_[i][0] += av[i]*wj[0]; g_[i][1] += av[i]*wj[1];
                g_[i][2] += av[i]*wj[2]; g_[i][3] += av[i]*wj[3];
            }
        }
        __syncthreads();
    }
    for (int qq = 0; qq < 4; ++qq){
        if (w == qq){
            #pragma unroll
            for (int i=0;i<8;++i){
                int tok = tg*8+i;
                #pragma unroll
                for (int j=0;j<4;++j){
                    int c = cg*4+j;
                    if (qq == 0) gacc[tok][c] = g_[i][j];
                    else gacc[tok][c] += g_[i][j];
                }
            }
        }
        __syncthreads();
    }
    {
        int tokr = tid >> 2;
        #pragma unroll
        for (int p = 0; p < 2; ++p){
            int f4 = (tid & 3) + 4*p;
            float4 v = ((const float4*)(tok_emb + (size_t)(t0 + tokr) * DSZ))[f4];
            int j = f4 * 4;
            agT[j+0][tokr] = v.x; agT[j+1][tokr] = v.y;
            agT[j+2][tokr] = v.z; agT[j+3][tokr] = v.w;
        }
        int c = tid & 31, tok8 = (tid >> 5) * 8;
        float bgc = bg[c];
        #pragma unroll
        for (int i=0;i<8;++i){
            int tok = tok8 + i;
            agT[32 + c][tok] = gelu_f(gacc[tok][c] + bgc);
        }
        int row = tid >> 2;
        #pragma unroll
        for (int p = 0; p < 4; ++p){
            int f4 = (tid & 3) + 4*p;
            ((float4*)wfs[row])[f4] = ((const float4*)(Wf + (size_t)row * FMZ))[f4];
        }
    }
    __syncthreads();
    {
        int tok = tid & 63, fq = tid >> 6;
        float u_[16];
        #pragma unroll
        for (int i=0;i<16;++i) u_[i]=0.f;
        for (int j = 0; j < 64; ++j){
            float a = agT[j][tok];
            float wv[16];
            *(float4*)&wv[0]  = ((float4*)wfs[j])[fq*4+0];
            *(float4*)&wv[4]  = ((float4*)wfs[j])[fq*4+1];
            *(float4*)&wv[8]  = ((float4*)wfs[j])[fq*4+2];
            *(float4*)&wv[12] = ((float4*)wfs[j])[fq*4+3];
            #pragma unroll
            for (int i=0;i<16;++i) u_[i] += a * wv[i];
        }
        #pragma unroll
        for (int i=0;i<16;++i){
            int f = fq*16+i;
            uT[f][tok] = gelu_f(u_[i] + bfv[f]);
        }
    }
    __syncthreads();
    {
        int tok = tid & 63, e = tid >> 6;
        float lt = 0.f;
        #pragma unroll 8
        for (int f = 0; f < 64; ++f) lt += uT[f][tok] * wrs[f][e];
        logit_s[tok][e] = lt + br[e];
    }
    __syncthreads();
    int my_e = 0, my_pos = 0;
    if (tid < 64){
        int tok = tid;
        float l0 = logit_s[tok][0], l1 = logit_s[tok][1];
        float l2 = logit_s[tok][2], l3 = logit_s[tok][3];
        float mx = fmaxf(fmaxf(l0,l1), fmaxf(l2,l3));
        float p0 = expf(l0-mx), p1 = expf(l1-mx), p2 = expf(l2-mx), p3 = expf(l3-mx);
        float inv = 1.0f / (p0+p1+p2+p3);
        int be = 0; float bp = p0;
        if (p1 > bp){ bp = p1; be = 1; }
        if (p2 > bp){ bp = p2; be = 2; }
        if (p3 > bp){ bp = p3; be = 3; }
        tprob[t0 + tok] = bp * inv;
        prob_s[tok][0] = p0*inv; prob_s[tok][1] = p1*inv;
        prob_s[tok][2] = p2*inv; prob_s[tok][3] = p3*inv;
        my_e = be;
        my_pos = atomicAdd(&lcnt[be], 1);
    }
    __syncthreads();
    if (tid < 4) lbase[tid] = atomicAdd(&cnt[tid], lcnt[tid]);
    __syncthreads();
    if (tid < 64) list[my_e * NTOK + lbase[my_e] + my_pos] = t0 + tid;
    if (tid < 4){
        float s = 0.f;
        for (int t = 0; t < 64; ++t) s += prob_s[t][tid];
        imp_part[blockIdx.x * 4 + tid] = s;
    }

    // ---- tail: h -> bf16 for this block's 64 rows (L2/L3-warm, coalesced)
    {
        int wv = tid >> 6, ll = tid & 63;
        for (int r = wv; r < 64; r += 4){
            const float4* src = (const float4*)(h + (size_t)(t0 + r) * HDIM);
            ushort4* dst = (ushort4*)(hbf + (size_t)(t0 + r) * HDIM);
            #pragma unroll
            for (int i = 0; i < 4; ++i){
                float4 v = src[ll + 64 * i];
                ushort4 o; o.x = f2bf(v.x); o.y = f2bf(v.y); o.z = f2bf(v.z); o.w = f2bf(v.w);
                dst[ll + 64 * i] = o;
            }
        }
    }
}

// ---------------- grouped GEMM v13: 128x64 tile, 4 waves x (32x64) wave-tiles ----------------
// 256 thr = 4 waves (4M x 1N); per-wave acc = 2x4 frags = 32 AGPR. LDS 24KB single-buffer.
// Raises MFMA:ds_read ratio to 16:12 (vs r16's 16:16) while keeping r16's small-footprint
// high-residency blocks (24KB -> 6 blocks/CU by LDS; VGPR ~60 -> 8 waves/SIMD by regs).
// Same verified 0-conflict swizzle (row&7 == l&7 both sides), flat live-tile dispatch,
// m204 bijective XCD swizzle. One variable changed vs r16: waves/block + wave N-width.
template<int KTD, int NT, bool PH1, int NWG, bool AGATHER>
__global__ __launch_bounds__(256) void k_gemm(
    const unsigned short* __restrict__ Abase,
    const unsigned short* __restrict__ Bbase,
    const int* __restrict__ list, const int* __restrict__ cnt_g,
    const float* __restrict__ bias,
    unsigned short* __restrict__ A1out,
    const float* __restrict__ hres,
    const float* __restrict__ tprob,
    float* __restrict__ outp)
{
    __shared__ __align__(16) unsigned short As[128 * 64];   // 16 KB
    __shared__ __align__(16) unsigned short Bs[64 * 64];    // 8 KB
    constexpr int GX = NT / 64;

    // m204 bijective XCD swizzle over the flat 1-D grid
    int p = blockIdx.x;
    int xcd = p & 7, pos = p >> 3;
    constexpr int Q = NWG >> 3, R = NWG & 7;
    int base = xcd < R ? xcd * (Q + 1) : R * (Q + 1) + (xcd - R) * Q;
    int fl = base + pos;
    int mt = fl / GX, nn = fl % GX;

    // active-tile prefix mapping: mt -> (expert e, packed base pb, local m-tile)
    int c0 = cnt_g[0], c1 = cnt_g[1], c2 = cnt_g[2], c3 = cnt_g[3];
    int nt0 = (c0 + 127) >> 7, nt1 = (c1 + 127) >> 7, nt2 = (c2 + 127) >> 7;
    int nt3 = (c3 + 127) >> 7;
    if (mt >= nt0 + nt1 + nt2 + nt3) return;
    int e = 0, pb = 0, mtl = mt, cnt = c0;
    if (mtl >= nt0){ mtl -= nt0; pb += c0; e = 1; cnt = c1;
        if (mtl >= nt1){ mtl -= nt1; pb += c1; e = 2; cnt = c2;
            if (mtl >= nt2){ mtl -= nt2; pb += c2; e = 3; cnt = c3; } } }
    int m0 = mtl * 128;
    int n0 = nn * 64;

    int tid = threadIdx.x, w = tid >> 6, l = tid & 63;
    int wr = w;                     // 4M x 1N wave grid; wave tile 32 x 64
    const int* lrow = list + e * NTOK;

    // staging: 256 threads; A 4 instrs (32 rows each), B 2 instrs; pre-swizzled source
    int srow = tid >> 3;            // 0..31
    int csw = ((tid & 7) ^ (srow & 7)) * 8;
    const unsigned short* aptr[4];
    #pragma unroll
    for (int i = 0; i < 4; ++i){
        int row = i * 32 + srow;
        int ga = m0 + row; if (ga > cnt - 1) ga = cnt - 1;
        size_t arow = AGATHER ? (size_t)lrow[ga] : (size_t)(pb + ga);
        aptr[i] = Abase + arow * KTD + csw;
    }
    const unsigned short* bptr[2];
    #pragma unroll
    for (int i = 0; i < 2; ++i)
        bptr[i] = Bbase + ((size_t)e * NT + (n0 + i * 32 + srow)) * KTD + csw;

    f32x4 acc[2][4] = {};
    int rsw = (l & 7) << 4;
    for (int k0 = 0; k0 < KTD; k0 += 64){
        gld_lds16(aptr[0] + k0, (char*)As + tid * 16);
        gld_lds16(aptr[1] + k0, (char*)As + 4096 + tid * 16);
        gld_lds16(aptr[2] + k0, (char*)As + 8192 + tid * 16);
        gld_lds16(aptr[3] + k0, (char*)As + 12288 + tid * 16);
        gld_lds16(bptr[0] + k0, (char*)Bs + tid * 16);
        gld_lds16(bptr[1] + k0, (char*)Bs + 4096 + tid * 16);
        __syncthreads();
        #pragma unroll
        for (int kk = 0; kk < 2; ++kk){
            bf16x8 a[2], b[4];
            #pragma unroll
            for (int m = 0; m < 2; ++m)
                a[m] = *(const bf16x8*)((const char*)As + (wr*32 + m*16 + (l&15))*128 + ((kk*64 + (l>>4)*16) ^ rsw));
            #pragma unroll
            for (int n = 0; n < 4; ++n)
                b[n] = *(const bf16x8*)((const char*)Bs + (n*16 + (l&15))*128 + ((kk*64 + (l>>4)*16) ^ rsw));
            #pragma unroll
            for (int m = 0; m < 2; ++m)
                #pragma unroll
                for (int n = 0; n < 4; ++n)
                    acc[m][n] = __builtin_amdgcn_mfma_f32_16x16x32_bf16(a[m], b[n], acc[m][n], 0, 0, 0);
        }
        __syncthreads();
    }

    // epilogue: C/D layout col = lane&15 (+16*n), row = (lane>>4)*4 + reg (+16*m)
    float bs[4];
    #pragma unroll
    for (int n = 0; n < 4; ++n)
        bs[n] = bias[e * NT + n0 + n * 16 + (l & 15)];
    #pragma unroll
    for (int m = 0; m < 2; ++m){
        #pragma unroll
        for (int r = 0; r < 4; ++r){
            int row = wr * 32 + m * 16 + (l >> 4) * 4 + r;
            int gg = m0 + row;
            if (gg < cnt){
                if (PH1){
                    #pragma unroll
                    for (int n = 0; n < 4; ++n){
                        int col = n0 + n * 16 + (l & 15);
                        float v = acc[m][n][r] + bs[n];
                        A1out[(size_t)(pb + gg) * FFZ + col] = f2bf(gelu_f(v));
                    }
                } else {
                    int tok = lrow[gg];
                    float sc = 0.5f * tprob[tok];
                    #pragma unroll
                    for (int n = 0; n < 4; ++n){
                        int col = n0 + n * 16 + (l & 15);
                        float v = acc[m][n][r] + bs[n];
                        size_t o = (size_t)tok * HDIM + col;
                        outp[o] = hres[o] + sc * v;
                    }
                }
            }
        }
    }
}

// ---------------- final: lb_loss ----------------
__global__ void k_final(const float* __restrict__ imp_part, const int* __restrict__ cnt,
                        float* __restrict__ outp){
    __shared__ float imp_s[4];
    int tid = threadIdx.x;
    if (tid < 4){
        float s = 0.f;
        for (int b = 0; b < 256; ++b) s += imp_part[b*4 + tid];
        imp_s[tid] = s;
    }
    __syncthreads();
    if (tid == 0){
        float lb = 0.f;
        #pragma unroll
        for (int e = 0; e < 4; ++e) lb += imp_s[e] * (float)cnt[e];
        outp[(size_t)NTOK * HDIM] = (float)NEXP * lb / ((float)NTOK * (float)NTOK + 1e-8f);
    }
}

extern "C" void kernel_launch(void* const* d_in, const int* in_sizes, int n_in,
                              void* d_out, int out_size, void* d_ws, size_t ws_size,
                              hipStream_t stream){
    const float* h       = (const float*)d_in[0];
    const float* tok_emb = (const float*)d_in[1];
    const float* ln_g = (const float*)d_in[3];
    const float* ln_b = (const float*)d_in[4];
    const float* Wg   = (const float*)d_in[5];
    const float* bg   = (const float*)d_in[6];
    const float* Wf   = (const float*)d_in[7];
    const float* bfv  = (const float*)d_in[8];
    const float* Wr   = (const float*)d_in[9];
    const float* br   = (const float*)d_in[10];
    const float* W1   = (const float*)d_in[11];
    const float* b1   = (const float*)d_in[12];
    const float* W2   = (const float*)d_in[13];
    const float* b2   = (const float*)d_in[14];
    float* outp = (float*)d_out;
    char* ws = (char*)d_ws;

    unsigned short* h_bf = (unsigned short*)(ws);               // 33554432 B  bf16(h), token order
    unsigned short* W1T  = (unsigned short*)(ws + 33554432);    // 16777216 B
    unsigned short* W2T  = (unsigned short*)(ws + 50331648);    // 16777216 B
    unsigned short* A1   = (unsigned short*)(ws + 67108864);    // 67108864 B  packed [NTOK][FFZ]
    float* tprob = (float*)(ws + 134348800);
    int*   list  = (int*)(ws + 134414336);                      // [E][NTOK]
    int*   cnt   = (int*)(ws + 134676480);                      // [E]
    float* imp   = (float*)(ws + 134676736);                    // [256][E]

    constexpr int NWG1 = (NTOK/128 + 3) * (FFZ/64);    // 4192
    constexpr int NWG2 = (NTOK/128 + 3) * (HDIM/64);   // 2096

    k_transpose2<<<dim3(64, 32, 8), dim3(32, 8), 0, stream>>>(W1, W2, W1T, W2T, cnt);
    k_route<<<NTOK/64, 256, 0, stream>>>(h, tok_emb, ln_g, ln_b, Wg, bg, Wf, bfv, Wr, br,
                                         tprob, list, cnt, imp, h_bf);
    k_gemm<HDIM, FFZ, true, NWG1, true><<<NWG1, 256, 0, stream>>>(
        h_bf, W1T, list, cnt, b1, A1, nullptr, nullptr, nullptr);
    k_gemm<FFZ, HDIM, false, NWG2, false><<<NWG2, 256, 0, stream>>>(
        A1, W2T, list, cnt, b2, nullptr, h, tprob, outp);
    k_final<<<1, 64, 0, stream>>>(imp, cnt, outp);
}

// Round 18
// 298.577 us; speedup vs baseline: 1.0012x; 1.0012x over previous
//
#include <hip/hip_runtime.h>
#include <hip/hip_bf16.h>
#include <math.h>

#define NTOK 16384
#define HDIM 1024
#define DSZ 32
#define DGZ 32
#define FMZ 64
#define NEXP 4
#define FFZ 2048

typedef __attribute__((ext_vector_type(4))) float f32x4;
typedef __attribute__((ext_vector_type(8))) short bf16x8;

__device__ __forceinline__ unsigned short f2bf(float f){
    union { float f; unsigned int u; } v; v.f = f;
    unsigned int r = (v.u + 0x7FFFu + ((v.u >> 16) & 1u)) >> 16;
    return (unsigned short)r;
}
__device__ __forceinline__ float gelu_f(float x){
    return 0.5f * x * (1.0f + erff(x * 0.70710678118654752440f));
}
__device__ __forceinline__ void gld_lds16(const void* g, void* s){
    __builtin_amdgcn_global_load_lds((const __attribute__((address_space(1))) unsigned int*)g,
                                     (__attribute__((address_space(3))) unsigned int*)s, 16, 0, 0);
}

// ---------------- kernel 1: both weight transposes in one launch (+ cnt zeroing) ----------------
__global__ __launch_bounds__(256) void k_transpose2(const float* __restrict__ W1,
        const float* __restrict__ W2, unsigned short* __restrict__ W1T,
        unsigned short* __restrict__ W2T, int* __restrict__ cnt){
    __shared__ float tile[32][33];
    if (blockIdx.x == 0 && blockIdx.y == 0 && blockIdx.z == 0 &&
        threadIdx.y == 0 && threadIdx.x < 4)
        cnt[threadIdx.x] = 0;
    int z = blockIdx.z;
    const float* in; unsigned short* out; int R, C, bx, by;
    if (z < 4){
        in = W1 + (size_t)z * HDIM * FFZ; out = W1T + (size_t)z * HDIM * FFZ;
        R = HDIM; C = FFZ; bx = blockIdx.x * 32; by = blockIdx.y * 32;
    } else {
        int e = z - 4;
        in = W2 + (size_t)e * FFZ * HDIM; out = W2T + (size_t)e * FFZ * HDIM;
        R = FFZ; C = HDIM; bx = blockIdx.y * 32; by = blockIdx.x * 32;
    }
    int x = threadIdx.x, y = threadIdx.y;
    #pragma unroll
    for (int i = 0; i < 32; i += 8)
        tile[y + i][x] = in[(size_t)(by + y + i) * C + (bx + x)];
    __syncthreads();
    #pragma unroll
    for (int i = 0; i < 32; i += 8)
        out[(size_t)(bx + y + i) * R + (by + x)] = f2bf(tile[x][y + i]);
}

// ---------------- kernel 2: fused routing (stats + route + h->bf16 conversion tail) ----------------
__global__ __launch_bounds__(256) void k_route(
    const float* __restrict__ h, const float* __restrict__ tok_emb,
    const float* __restrict__ ln_g, const float* __restrict__ ln_b,
    const float* __restrict__ Wg, const float* __restrict__ bg,
    const float* __restrict__ Wf, const float* __restrict__ bfv,
    const float* __restrict__ Wr, const float* __restrict__ br,
    float* __restrict__ tprob, int* __restrict__ list, int* __restrict__ cnt,
    float* __restrict__ imp_part, unsigned short* __restrict__ hbf)
{
    __shared__ __align__(16) char smem[62208];
    float* lgs  = (float*)(smem);
    float* lbs  = (float*)(smem + 4096);
    float (*hsT)[64]  = (float(*)[64])(smem + 8192);
    float (*wgs)[32]  = (float(*)[32])(smem + 24576);
    float (*gacc)[32] = (float(*)[32])(smem + 32768);
    float* mus = (float*)(smem + 40960);
    float* rss = (float*)(smem + 41216);
    float (*wrs)[4]     = (float(*)[4])(smem + 41472);
    float (*logit_s)[5] = (float(*)[5])(smem + 42496);
    float (*prob_s)[5]  = (float(*)[5])(smem + 43776);
    int* lcnt  = (int*)(smem + 45056);
    int* lbase = (int*)(smem + 45072);
    float (*agT)[64] = (float(*)[64])(smem);
    float (*wfs)[64] = (float(*)[64])(smem + 16384);
    float (*uT)[64]  = (float(*)[64])(smem + 45824);

    int tid = threadIdx.x;
    int t0 = blockIdx.x * 64;

    ((float4*)lgs)[tid] = ((const float4*)ln_g)[tid];
    ((float4*)lbs)[tid] = ((const float4*)ln_b)[tid];
    if (tid < 64) ((float4*)wrs)[tid] = ((const float4*)Wr)[tid];
    if (tid < 4) lcnt[tid] = 0;

    {
        int tokrow = tid >> 2, q4 = tid & 3;
        const float4* hp = (const float4*)(h + (size_t)(t0 + tokrow) * HDIM);
        float s = 0.f, s2 = 0.f;
        #pragma unroll 8
        for (int i = 0; i < 64; ++i){
            float4 v = hp[q4 + 4 * i];
            s  += v.x + v.y + v.z + v.w;
            s2 += v.x*v.x + v.y*v.y + v.z*v.z + v.w*v.w;
        }
        s  += __shfl_xor(s, 1, 64);  s2 += __shfl_xor(s2, 1, 64);
        s  += __shfl_xor(s, 2, 64);  s2 += __shfl_xor(s2, 2, 64);
        if (q4 == 0){
            float mu = s * (1.0f / HDIM);
            float var = fmaxf(s2 * (1.0f / HDIM) - mu * mu, 0.f);
            mus[tokrow] = mu;
            rss[tokrow] = 1.0f / sqrtf(var + 1e-5f);
        }
    }
    __syncthreads();

    int l = tid & 63, w = tid >> 6;
    int tg = l & 7, cg = l >> 3, q = w;
    float g_[8][4];
    #pragma unroll
    for (int i=0;i<8;++i){ g_[i][0]=0.f; g_[i][1]=0.f; g_[i][2]=0.f; g_[i][3]=0.f; }
    int tokrow = tid >> 2;
    float m_ = mus[tokrow], r_ = rss[tokrow];
    const float* hrow = h + (size_t)(t0 + tokrow) * HDIM;

    for (int k0 = 0; k0 < HDIM; k0 += 64){
        #pragma unroll
        for (int p = 0; p < 4; ++p){
            int f4 = (tid & 3) + 4 * p;
            float4 v = ((const float4*)(hrow + k0))[f4];
            int c = f4 * 4;
            hsT[c+0][tokrow] = (v.x - m_) * r_ * lgs[k0+c+0] + lbs[k0+c+0];
            hsT[c+1][tokrow] = (v.y - m_) * r_ * lgs[k0+c+1] + lbs[k0+c+1];
            hsT[c+2][tokrow] = (v.z - m_) * r_ * lgs[k0+c+2] + lbs[k0+c+2];
            hsT[c+3][tokrow] = (v.w - m_) * r_ * lgs[k0+c+3] + lbs[k0+c+3];
        }
        {
            int wgrow = tid >> 2;
            #pragma unroll
            for (int p = 0; p < 2; ++p){
                int f4 = (tid & 3) + 4 * p;
                ((float4*)wgs[wgrow])[f4] = ((const float4*)(Wg + (size_t)(k0 + wgrow) * DGZ))[f4];
            }
        }
        __syncthreads();
        #pragma unroll
        for (int kk16 = 0; kk16 < 16; ++kk16){
            int kk = q * 16 + kk16;
            float4 a0 = ((float4*)hsT[kk])[tg*2];
            float4 a1 = ((float4*)hsT[kk])[tg*2+1];
            float4 wv = ((float4*)wgs[kk])[cg];
            float av[8] = {a0.x,a0.y,a0.z,a0.w,a1.x,a1.y,a1.z,a1.w};
            float wj[4] = {wv.x,wv.y,wv.z,wv.w};
            #pragma unroll
            for (int i=0;i<8;++i){
                g_[i][0] += av[i]*wj[0]; g_[i][1] += av[i]*wj[1];
                g_[i][2] += av[i]*wj[2]; g_[i][3] += av[i]*wj[3];
            }
        }
        __syncthreads();
    }
    for (int qq = 0; qq < 4; ++qq){
        if (w == qq){
            #pragma unroll
            for (int i=0;i<8;++i){
                int tok = tg*8+i;
                #pragma unroll
                for (int j=0;j<4;++j){
                    int c = cg*4+j;
                    if (qq == 0) gacc[tok][c] = g_[i][j];
                    else gacc[tok][c] += g_[i][j];
                }
            }
        }
        __syncthreads();
    }
    {
        int tokr = tid >> 2;
        #pragma unroll
        for (int p = 0; p < 2; ++p){
            int f4 = (tid & 3) + 4*p;
            float4 v = ((const float4*)(tok_emb + (size_t)(t0 + tokr) * DSZ))[f4];
            int j = f4 * 4;
            agT[j+0][tokr] = v.x; agT[j+1][tokr] = v.y;
            agT[j+2][tokr] = v.z; agT[j+3][tokr] = v.w;
        }
        int c = tid & 31, tok8 = (tid >> 5) * 8;
        float bgc = bg[c];
        #pragma unroll
        for (int i=0;i<8;++i){
            int tok = tok8 + i;
            agT[32 + c][tok] = gelu_f(gacc[tok][c] + bgc);
        }
        int row = tid >> 2;
        #pragma unroll
        for (int p = 0; p < 4; ++p){
            int f4 = (tid & 3) + 4*p;
            ((float4*)wfs[row])[f4] = ((const float4*)(Wf + (size_t)row * FMZ))[f4];
        }
    }
    __syncthreads();
    {
        int tok = tid & 63, fq = tid >> 6;
        float u_[16];
        #pragma unroll
        for (int i=0;i<16;++i) u_[i]=0.f;
        for (int j = 0; j < 64; ++j){
            float a = agT[j][tok];
            float wv[16];
            *(float4*)&wv[0]  = ((float4*)wfs[j])[fq*4+0];
            *(float4*)&wv[4]  = ((float4*)wfs[j])[fq*4+1];
            *(float4*)&wv[8]  = ((float4*)wfs[j])[fq*4+2];
            *(float4*)&wv[12] = ((float4*)wfs[j])[fq*4+3];
            #pragma unroll
            for (int i=0;i<16;++i) u_[i] += a * wv[i];
        }
        #pragma unroll
        for (int i=0;i<16;++i){
            int f = fq*16+i;
            uT[f][tok] = gelu_f(u_[i] + bfv[f]);
        }
    }
    __syncthreads();
    {
        int tok = tid & 63, e = tid >> 6;
        float lt = 0.f;
        #pragma unroll 8
        for (int f = 0; f < 64; ++f) lt += uT[f][tok] * wrs[f][e];
        logit_s[tok][e] = lt + br[e];
    }
    __syncthreads();
    int my_e = 0, my_pos = 0;
    if (tid < 64){
        int tok = tid;
        float l0 = logit_s[tok][0], l1 = logit_s[tok][1];
        float l2 = logit_s[tok][2], l3 = logit_s[tok][3];
        float mx = fmaxf(fmaxf(l0,l1), fmaxf(l2,l3));
        float p0 = expf(l0-mx), p1 = expf(l1-mx), p2 = expf(l2-mx), p3 = expf(l3-mx);
        float inv = 1.0f / (p0+p1+p2+p3);
        int be = 0; float bp = p0;
        if (p1 > bp){ bp = p1; be = 1; }
        if (p2 > bp){ bp = p2; be = 2; }
        if (p3 > bp){ bp = p3; be = 3; }
        tprob[t0 + tok] = bp * inv;
        prob_s[tok][0] = p0*inv; prob_s[tok][1] = p1*inv;
        prob_s[tok][2] = p2*inv; prob_s[tok][3] = p3*inv;
        my_e = be;
        my_pos = atomicAdd(&lcnt[be], 1);
    }
    __syncthreads();
    if (tid < 4) lbase[tid] = atomicAdd(&cnt[tid], lcnt[tid]);
    __syncthreads();
    if (tid < 64) list[my_e * NTOK + lbase[my_e] + my_pos] = t0 + tid;
    if (tid < 4){
        float s = 0.f;
        for (int t = 0; t < 64; ++t) s += prob_s[t][tid];
        imp_part[blockIdx.x * 4 + tid] = s;
    }

    // ---- tail: h -> bf16 for this block's 64 rows (L2/L3-warm, coalesced)
    {
        int wv = tid >> 6, ll = tid & 63;
        for (int r = wv; r < 64; r += 4){
            const float4* src = (const float4*)(h + (size_t)(t0 + r) * HDIM);
            ushort4* dst = (ushort4*)(hbf + (size_t)(t0 + r) * HDIM);
            #pragma unroll
            for (int i = 0; i < 4; ++i){
                float4 v = src[ll + 64 * i];
                ushort4 o; o.x = f2bf(v.x); o.y = f2bf(v.y); o.z = f2bf(v.z); o.w = f2bf(v.w);
                dst[ll + 64 * i] = o;
            }
        }
    }
}

// ---------------- grouped GEMM v12 (SESSION BEST, r16): 128x64 tile, 8 waves x (32x32) ----------------
// 512 thr = 8 waves (4M x 2N); per-wave acc = 2x2 frags = 16 AGPR; VGPR 28 -> occupancy 76%.
// LDS 24KB single-buffer, plain __syncthreads() (compiler-scheduled waits).
// Small tiles double live-block count (GEMM1 ~4.1/CU, GEMM2 ~2.1/CU) -- the TLP lever
// (r11/r15/r16) that provided every real gain this session. Verified 0-conflict swizzle
// (row&7 == l&7 both sides), flat live-tile dispatch, m204 bijective XCD swizzle
// (n-fastest keeps the A m-panel L2-hot across re-reads).
template<int KTD, int NT, bool PH1, int NWG, bool AGATHER>
__global__ __launch_bounds__(512) void k_gemm(
    const unsigned short* __restrict__ Abase,
    const unsigned short* __restrict__ Bbase,
    const int* __restrict__ list, const int* __restrict__ cnt_g,
    const float* __restrict__ bias,
    unsigned short* __restrict__ A1out,
    const float* __restrict__ hres,
    const float* __restrict__ tprob,
    float* __restrict__ outp)
{
    __shared__ __align__(16) unsigned short As[128 * 64];   // 16 KB
    __shared__ __align__(16) unsigned short Bs[64 * 64];    // 8 KB
    constexpr int GX = NT / 64;

    // m204 bijective XCD swizzle over the flat 1-D grid
    int p = blockIdx.x;
    int xcd = p & 7, pos = p >> 3;
    constexpr int Q = NWG >> 3, R = NWG & 7;
    int base = xcd < R ? xcd * (Q + 1) : R * (Q + 1) + (xcd - R) * Q;
    int fl = base + pos;
    int mt = fl / GX, nn = fl % GX;

    // active-tile prefix mapping: mt -> (expert e, packed base pb, local m-tile)
    int c0 = cnt_g[0], c1 = cnt_g[1], c2 = cnt_g[2], c3 = cnt_g[3];
    int nt0 = (c0 + 127) >> 7, nt1 = (c1 + 127) >> 7, nt2 = (c2 + 127) >> 7;
    int nt3 = (c3 + 127) >> 7;
    if (mt >= nt0 + nt1 + nt2 + nt3) return;
    int e = 0, pb = 0, mtl = mt, cnt = c0;
    if (mtl >= nt0){ mtl -= nt0; pb += c0; e = 1; cnt = c1;
        if (mtl >= nt1){ mtl -= nt1; pb += c1; e = 2; cnt = c2;
            if (mtl >= nt2){ mtl -= nt2; pb += c2; e = 3; cnt = c3; } } }
    int m0 = mtl * 128;
    int n0 = nn * 64;

    int tid = threadIdx.x, w = tid >> 6, l = tid & 63;
    int wr = w >> 1, wc = w & 1;     // 4M x 2N wave grid; wave tile 32 x 32
    const int* lrow = list + e * NTOK;

    // staging: A 2 instrs (rows i*64 + tid>>3), B 1 instr (rows tid>>3); pre-swizzled source
    int srow = tid >> 3;
    int csw = ((tid & 7) ^ (srow & 7)) * 8;
    const unsigned short* aptr[2];
    #pragma unroll
    for (int i = 0; i < 2; ++i){
        int row = i * 64 + srow;
        int ga = m0 + row; if (ga > cnt - 1) ga = cnt - 1;
        size_t arow = AGATHER ? (size_t)lrow[ga] : (size_t)(pb + ga);
        aptr[i] = Abase + arow * KTD + csw;
    }
    const unsigned short* bptr = Bbase + ((size_t)e * NT + (n0 + srow)) * KTD + csw;

    f32x4 acc[2][2] = {};
    int rsw = (l & 7) << 4;
    for (int k0 = 0; k0 < KTD; k0 += 64){
        gld_lds16(aptr[0] + k0, (char*)As + tid * 16);
        gld_lds16(aptr[1] + k0, (char*)As + 8192 + tid * 16);
        gld_lds16(bptr + k0,    (char*)Bs + tid * 16);
        __syncthreads();
        #pragma unroll
        for (int kk = 0; kk < 2; ++kk){
            bf16x8 a[2], b[2];
            #pragma unroll
            for (int m = 0; m < 2; ++m)
                a[m] = *(const bf16x8*)((const char*)As + (wr*32 + m*16 + (l&15))*128 + ((kk*64 + (l>>4)*16) ^ rsw));
            #pragma unroll
            for (int n = 0; n < 2; ++n)
                b[n] = *(const bf16x8*)((const char*)Bs + (wc*32 + n*16 + (l&15))*128 + ((kk*64 + (l>>4)*16) ^ rsw));
            #pragma unroll
            for (int m = 0; m < 2; ++m)
                #pragma unroll
                for (int n = 0; n < 2; ++n)
                    acc[m][n] = __builtin_amdgcn_mfma_f32_16x16x32_bf16(a[m], b[n], acc[m][n], 0, 0, 0);
        }
        __syncthreads();
    }

    // epilogue: C/D layout col = lane&15 (+16*n), row = (lane>>4)*4 + reg (+16*m)
    float bs[2];
    #pragma unroll
    for (int n = 0; n < 2; ++n)
        bs[n] = bias[e * NT + n0 + wc * 32 + n * 16 + (l & 15)];
    #pragma unroll
    for (int m = 0; m < 2; ++m){
        #pragma unroll
        for (int r = 0; r < 4; ++r){
            int row = wr * 32 + m * 16 + (l >> 4) * 4 + r;
            int gg = m0 + row;
            if (gg < cnt){
                if (PH1){
                    #pragma unroll
                    for (int n = 0; n < 2; ++n){
                        int col = n0 + wc * 32 + n * 16 + (l & 15);
                        float v = acc[m][n][r] + bs[n];
                        A1out[(size_t)(pb + gg) * FFZ + col] = f2bf(gelu_f(v));
                    }
                } else {
                    int tok = lrow[gg];
                    float sc = 0.5f * tprob[tok];
                    #pragma unroll
                    for (int n = 0; n < 2; ++n){
                        int col = n0 + wc * 32 + n * 16 + (l & 15);
                        float v = acc[m][n][r] + bs[n];
                        size_t o = (size_t)tok * HDIM + col;
                        outp[o] = hres[o] + sc * v;
                    }
                }
            }
        }
    }
}

// ---------------- final: lb_loss ----------------
__global__ void k_final(const float* __restrict__ imp_part, const int* __restrict__ cnt,
                        float* __restrict__ outp){
    __shared__ float imp_s[4];
    int tid = threadIdx.x;
    if (tid < 4){
        float s = 0.f;
        for (int b = 0; b < 256; ++b) s += imp_part[b*4 + tid];
        imp_s[tid] = s;
    }
    __syncthreads();
    if (tid == 0){
        float lb = 0.f;
        #pragma unroll
        for (int e = 0; e < 4; ++e) lb += imp_s[e] * (float)cnt[e];
        outp[(size_t)NTOK * HDIM] = (float)NEXP * lb / ((float)NTOK * (float)NTOK + 1e-8f);
    }
}

extern "C" void kernel_launch(void* const* d_in, const int* in_sizes, int n_in,
                              void* d_out, int out_size, void* d_ws, size_t ws_size,
                              hipStream_t stream){
    const float* h       = (const float*)d_in[0];
    const float* tok_emb = (const float*)d_in[1];
    const float* ln_g = (const float*)d_in[3];
    const float* ln_b = (const float*)d_in[4];
    const float* Wg   = (const float*)d_in[5];
    const float* bg   = (const float*)d_in[6];
    const float* Wf   = (const float*)d_in[7];
    const float* bfv  = (const float*)d_in[8];
    const float* Wr   = (const float*)d_in[9];
    const float* br   = (const float*)d_in[10];
    const float* W1   = (const float*)d_in[11];
    const float* b1   = (const float*)d_in[12];
    const float* W2   = (const float*)d_in[13];
    const float* b2   = (const float*)d_in[14];
    float* outp = (float*)d_out;
    char* ws = (char*)d_ws;

    unsigned short* h_bf = (unsigned short*)(ws);               // 33554432 B  bf16(h), token order
    unsigned short* W1T  = (unsigned short*)(ws + 33554432);    // 16777216 B
    unsigned short* W2T  = (unsigned short*)(ws + 50331648);    // 16777216 B
    unsigned short* A1   = (unsigned short*)(ws + 67108864);    // 67108864 B  packed [NTOK][FFZ]
    float* tprob = (float*)(ws + 134348800);
    int*   list  = (int*)(ws + 134414336);                      // [E][NTOK]
    int*   cnt   = (int*)(ws + 134676480);                      // [E]
    float* imp   = (float*)(ws + 134676736);                    // [256][E]

    constexpr int NWG1 = (NTOK/128 + 3) * (FFZ/64);    // 4192
    constexpr int NWG2 = (NTOK/128 + 3) * (HDIM/64);   // 2096

    k_transpose2<<<dim3(64, 32, 8), dim3(32, 8), 0, stream>>>(W1, W2, W1T, W2T, cnt);
    k_route<<<NTOK/64, 256, 0, stream>>>(h, tok_emb, ln_g, ln_b, Wg, bg, Wf, bfv, Wr, br,
                                         tprob, list, cnt, imp, h_bf);
    k_gemm<HDIM, FFZ, true, NWG1, true><<<NWG1, 512, 0, stream>>>(
        h_bf, W1T, list, cnt, b1, A1, nullptr, nullptr, nullptr);
    k_gemm<FFZ, HDIM, false, NWG2, false><<<NWG2, 512, 0, stream>>>(
        A1, W2T, list, cnt, b2, nullptr, h, tprob, outp);
    k_final<<<1, 64, 0, stream>>>(imp, cnt, outp);
}